// Round 4
// baseline (207.073 us; speedup 1.0000x reference)
//
#include <hip/hip_runtime.h>

// LSTM (B=8192, T=512, H=5) + MLP 5->32->32->5, fp32.
// Round 13: fenced schedule — fill the exposed chain tail.
//  - R12 post-mortem: wall ~= issue + chain with ~ZERO overlap (330+168
//    ~= 487 measured). The list scheduler drains all slack work early;
//    the serial tail (rcp->c->exp2->rcp->tanh->h->DPP) runs exposed.
//  - Fix: phase the step with __builtin_amdgcn_sched_barrier(0) fences
//    that RESERVE the x-part FMAs for the trans-latency windows. Pure
//    VALU body -> pinning is safe (no waitcnt interactions).
//  - 2-deep zx pipeline: step t computes x-part of t+2, so fillers have
//    slack to sit in t's tail windows.
//  - 2-way rcp combines: i*g = (A2-2)*rcp(A0*A2); f,o share rcp(A1*A3).
//    -2 trans/step (32 issue cyc). Overflow-safe (products <= 2^65).
//  - Tail: h = fmaf(-2o, rc, o), 2o precomputed in a filler window.
//  - Keeps: freed allocator (R10), DPP broadcast (R9), LDS x-staging
//    RSTR=164 (R8), pre-folded scales (R7).

#define LOG2E 1.44269504088896f

__device__ __forceinline__ float hexp2(float x) { return __builtin_amdgcn_exp2f(x); }
__device__ __forceinline__ float hrcp(float x)  { return __builtin_amdgcn_rcpf(x); }
#define SBAR() __builtin_amdgcn_sched_barrier(0)

template<int CTRL>
__device__ __forceinline__ float dpp_mov(float x) {
  int r = __builtin_amdgcn_update_dpp(0, __builtin_bit_cast(int, x),
                                      CTRL, 0xF, 0xF, true);
  return __builtin_bit_cast(float, r);
}
template<int CTRL, int BANKMASK>
__device__ __forceinline__ float dpp_merge(float old, float src) {
  int r = __builtin_amdgcn_update_dpp(__builtin_bit_cast(int, old),
                                      __builtin_bit_cast(int, src),
                                      CTRL, 0xF, BANKMASK, false);
  return __builtin_bit_cast(float, r);
}

constexpr int TT   = 512;
constexpr int HD   = 5;
constexpr int RPB  = 8;     // rows per wave (8 lanes each)
constexpr int CHNK = 32;    // steps per LDS chunk
constexpr int RSTR = 164;   // padded LDS row stride
constexpr int XOFF = RPB * RSTR;
constexpr int NCH  = TT / CHNK;

__global__ __attribute__((amdgpu_flat_work_group_size(64, 64),
                          amdgpu_waves_per_eu(1, 1)))
void lstm_mlp_kernel(
    const float* __restrict__ x,   const float* __restrict__ Wih,
    const float* __restrict__ Whh, const float* __restrict__ bih,
    const float* __restrict__ bhh, const float* __restrict__ W1,
    const float* __restrict__ b1,  const float* __restrict__ W2,
    const float* __restrict__ b2,  const float* __restrict__ W3,
    const float* __restrict__ b3,  float* __restrict__ out, int B)
{
  const int lane = threadIdx.x;
  const int grp  = lane >> 3;           // row within block (0..7)
  const int j    = lane & 7;            // unit owned (valid if j<5)
  const int jj   = (j < 5) ? j : 0;
  const int blockRow = blockIdx.x * RPB;
  const int row  = blockRow + grp;
  const bool act = (j < 5) && (row < B);

  __shared__ __align__(16) float xbuf[2 * XOFF];
  __shared__ float s1[RPB][32];
  __shared__ float s2[RPB][32];

  // ---- per-lane weights (rows {j,5+j,10+j,15+j}), activation pre-scaled --
  float wih[4][5], whh[4][5], bsum[4];
#pragma unroll
  for (int G = 0; G < 4; ++G) {
    const float sc = (G == 2) ? (2.0f * LOG2E) : (-LOG2E);
#pragma unroll
    for (int k = 0; k < 5; ++k) {
      wih[G][k] = Wih[(G * 5 + jj) * 5 + k] * sc;
      whh[G][k] = Whh[(G * 5 + jj) * 5 + k] * sc;
    }
    bsum[G] = (bih[G * 5 + jj] + bhh[G * 5 + jj]) * sc;
  }

  const int rowc = (row < B) ? row : (B - 1);
  const float xl0 = x[(size_t)rowc * (TT * HD) + 511 * HD + 0];
  const float xl1 = x[(size_t)rowc * (TT * HD) + 511 * HD + 1];
  const float xl2 = x[(size_t)rowc * (TT * HD) + 511 * HD + 2];
  const float xl3 = x[(size_t)rowc * (TT * HD) + 511 * HD + 3];
  const float xl4 = x[(size_t)rowc * (TT * HD) + 511 * HD + 4];

  // ---- staging: 5x16B per lane per 32-step chunk (R8-proven) ----
  const float4* gp[5];
  int wa[5];
#pragma unroll
  for (int i = 0; i < 5; ++i) {
    int u  = i * 64 + lane;
    int r  = u / 40;
    int o4 = u - r * 40;
    int gr = blockRow + r; if (gr >= B) gr = B - 1;
    gp[i]  = (const float4*)(x + (size_t)gr * (TT * HD)) + o4;
    wa[i]  = r * RSTR + o4 * 4;
  }

  float4 st0, st1, st2, st3, st4;
  st0 = *gp[0]; gp[0] += 40; st1 = *gp[1]; gp[1] += 40;
  st2 = *gp[2]; gp[2] += 40; st3 = *gp[3]; gp[3] += 40;
  st4 = *gp[4]; gp[4] += 40;
  *(float4*)&xbuf[wa[0]] = st0; *(float4*)&xbuf[wa[1]] = st1;
  *(float4*)&xbuf[wa[2]] = st2; *(float4*)&xbuf[wa[3]] = st3;
  *(float4*)&xbuf[wa[4]] = st4;
  st0 = *gp[0]; gp[0] += 40; st1 = *gp[1]; gp[1] += 40;
  st2 = *gp[2]; gp[2] += 40; st3 = *gp[3]; gp[3] += 40;
  st4 = *gp[4]; gp[4] += 40;

  // ---- recurrence state ----
  float c = 0.0f;
  float hv0 = 0.f, hv1 = 0.f, hv2 = 0.f, hv3 = 0.f, hv4 = 0.f;
  // 2-deep x-part queue: zxA = current step, zxB = next step
  float zxA0, zxA1, zxA2, zxA3;
  float zxB0, zxB1, zxB2, zxB3;

  // prologue: zx for steps 0 and 1 from the just-written chunk-0 buffer
  {
    const float* xp = &xbuf[grp * RSTR];
#pragma unroll
    for (int s = 0; s < 2; ++s) {
      float p0 = xp[5*s+0], p1 = xp[5*s+1], p2 = xp[5*s+2],
            p3 = xp[5*s+3], p4 = xp[5*s+4];
      float t0 = bsum[0], t1 = bsum[1], t2 = bsum[2], t3 = bsum[3];
      t0 = fmaf(p0, wih[0][0], t0); t0 = fmaf(p1, wih[0][1], t0);
      t0 = fmaf(p2, wih[0][2], t0); t0 = fmaf(p3, wih[0][3], t0);
      t0 = fmaf(p4, wih[0][4], t0);
      t1 = fmaf(p0, wih[1][0], t1); t1 = fmaf(p1, wih[1][1], t1);
      t1 = fmaf(p2, wih[1][2], t1); t1 = fmaf(p3, wih[1][3], t1);
      t1 = fmaf(p4, wih[1][4], t1);
      t2 = fmaf(p0, wih[2][0], t2); t2 = fmaf(p1, wih[2][1], t2);
      t2 = fmaf(p2, wih[2][2], t2); t2 = fmaf(p3, wih[2][3], t2);
      t2 = fmaf(p4, wih[2][4], t2);
      t3 = fmaf(p0, wih[3][0], t3); t3 = fmaf(p1, wih[3][1], t3);
      t3 = fmaf(p2, wih[3][2], t3); t3 = fmaf(p3, wih[3][3], t3);
      t3 = fmaf(p4, wih[3][4], t3);
      if (s == 0) { zxA0 = t0; zxA1 = t1; zxA2 = t2; zxA3 = t3; }
      else        { zxB0 = t0; zxB1 = t1; zxB2 = t2; zxB3 = t3; }
    }
  }

  // fenced pipelined step: consumes zxA (step t), computes x-part of
  // step t+2 from n0..n4 inside t's trans-latency windows.
  auto stepP = [&](float n0, float n1, float n2, float n3, float n4) {
    // P1: h-dots (chain head), order bias->x (in zx) ->h0..h4 preserved
    float z0 = zxA0, z1 = zxA1, z2 = zxA2, z3 = zxA3;
    z0 = fmaf(hv0, whh[0][0], z0); z0 = fmaf(hv1, whh[0][1], z0);
    z0 = fmaf(hv2, whh[0][2], z0); z0 = fmaf(hv3, whh[0][3], z0);
    z0 = fmaf(hv4, whh[0][4], z0);
    z1 = fmaf(hv0, whh[1][0], z1); z1 = fmaf(hv1, whh[1][1], z1);
    z1 = fmaf(hv2, whh[1][2], z1); z1 = fmaf(hv3, whh[1][3], z1);
    z1 = fmaf(hv4, whh[1][4], z1);
    z2 = fmaf(hv0, whh[2][0], z2); z2 = fmaf(hv1, whh[2][1], z2);
    z2 = fmaf(hv2, whh[2][2], z2); z2 = fmaf(hv3, whh[2][3], z2);
    z2 = fmaf(hv4, whh[2][4], z2);
    z3 = fmaf(hv0, whh[3][0], z3); z3 = fmaf(hv1, whh[3][1], z3);
    z3 = fmaf(hv2, whh[3][2], z3); z3 = fmaf(hv3, whh[3][3], z3);
    z3 = fmaf(hv4, whh[3][4], z3);
    // P2: exps, g-gate first (it heads the c-chain)
    float e2 = hexp2(z2);
    float e0 = hexp2(z0);
    float e1 = hexp2(z1);
    float e3 = hexp2(z3);
    SBAR();
    // F1: x-part(t+2) gates 0,1 — fills exp latency
    float n_0 = bsum[0];
    n_0 = fmaf(n0, wih[0][0], n_0); n_0 = fmaf(n1, wih[0][1], n_0);
    n_0 = fmaf(n2, wih[0][2], n_0); n_0 = fmaf(n3, wih[0][3], n_0);
    n_0 = fmaf(n4, wih[0][4], n_0);
    float n_1 = bsum[1];
    n_1 = fmaf(n0, wih[1][0], n_1); n_1 = fmaf(n1, wih[1][1], n_1);
    n_1 = fmaf(n2, wih[1][2], n_1); n_1 = fmaf(n3, wih[1][3], n_1);
    n_1 = fmaf(n4, wih[1][4], n_1);
    SBAR();
    // P3: combined denominators + 2 rcps
    float A2 = 1.0f + e2;
    float A0 = 1.0f + e0;
    float m02 = A0 * A2;
    float r02 = hrcp(m02);
    float A1 = 1.0f + e1;
    float A3 = 1.0f + e3;
    float m13 = A1 * A3;
    float r13 = hrcp(m13);
    SBAR();
    // F2: x-part(t+2) gate 2 — fills rcp latency
    float n_2 = bsum[2];
    n_2 = fmaf(n0, wih[2][0], n_2); n_2 = fmaf(n1, wih[2][1], n_2);
    n_2 = fmaf(n2, wih[2][2], n_2); n_2 = fmaf(n3, wih[2][3], n_2);
    n_2 = fmaf(n4, wih[2][4], n_2);
    SBAR();
    // P4: gates + c-update + exp2(c)
    float t2g = A2 - 2.0f;
    float ig  = t2g * r02;        // i*g
    float fg  = A3 * r13;         // f
    float og  = A1 * r13;         // o
    c = fmaf(fg, c, ig);
    float ec = hexp2(c * (2.0f * LOG2E));
    SBAR();
    // F3: x-part(t+2) gate 3 + 2*o — fills exp2(c) latency
    float n_3 = bsum[3];
    n_3 = fmaf(n0, wih[3][0], n_3); n_3 = fmaf(n1, wih[3][1], n_3);
    n_3 = fmaf(n2, wih[3][2], n_3); n_3 = fmaf(n3, wih[3][3], n_3);
    n_3 = fmaf(n4, wih[3][4], n_3);
    float o2 = og + og;
    SBAR();
    // P5: tanh(c) rcp
    float Ac = 1.0f + ec;
    float rc = hrcp(Ac);
    // P6: h and broadcast (chain tail; nothing left to fill)
    float h = fmaf(-o2, rc, og);
    float q0 = dpp_mov<0x00>(h);
    float q1 = dpp_mov<0x55>(h);
    float q2 = dpp_mov<0xAA>(h);
    float q3 = dpp_mov<0xFF>(h);
    hv0 = dpp_merge<0x114, 0xA>(q0, q0);
    hv1 = dpp_merge<0x114, 0xA>(q1, q1);
    hv2 = dpp_merge<0x114, 0xA>(q2, q2);
    hv3 = dpp_merge<0x114, 0xA>(q3, q3);
    hv4 = dpp_merge<0x104, 0x5>(q0, q0);
    // rotate the zx queue (register renames, free)
    zxA0 = zxB0; zxA1 = zxB1; zxA2 = zxB2; zxA3 = zxB3;
    zxB0 = n_0;  zxB1 = n_1;  zxB2 = n_2;  zxB3 = n_3;
  };

  float4 A0v, A1v, A2v, A3v, A4v;
  float4 B0v, B1v, B2v, B3v, B4v;

  auto rdg = [&](int fi, float4& Av, float4& Bv, float4& Cv, float4& Dv, float4& Ev) {
    const float4* p = (const float4*)&xbuf[fi];
    Av = p[0]; Bv = p[1]; Cv = p[2]; Dv = p[3]; Ev = p[4];
  };

  // SUBA: steps a..a+3; fillers = x(a+2..a+5) = A elems 10..19 + B elems 0..9
  auto SUBA = [&]() {
    stepP(A2v.z, A2v.w, A3v.x, A3v.y, A3v.z);
    stepP(A3v.w, A4v.x, A4v.y, A4v.z, A4v.w);
    stepP(B0v.x, B0v.y, B0v.z, B0v.w, B1v.x);
    stepP(B1v.y, B1v.z, B1v.w, B2v.x, B2v.y);
  };
  // SUBB: steps b..b+3; fillers = x(b+2..b+5) = B elems 10..19 + (refreshed) A elems 0..9
  auto SUBB = [&]() {
    stepP(B2v.z, B2v.w, B3v.x, B3v.y, B3v.z);
    stepP(B3v.w, B4v.x, B4v.y, B4v.z, B4v.w);
    stepP(A0v.x, A0v.y, A0v.z, A0v.w, A1v.x);
    stepP(A1v.y, A1v.z, A1v.w, A2v.x, A2v.y);
  };

#pragma unroll 1
  for (int ch = 0; ch < NCH; ++ch) {
    const int bo_cur  = (ch & 1) ? XOFF : 0;
    const int bo_next = XOFF - bo_cur;
    if (ch < NCH - 1) {
      *(float4*)&xbuf[wa[0] + bo_next] = st0;
      *(float4*)&xbuf[wa[1] + bo_next] = st1;
      *(float4*)&xbuf[wa[2] + bo_next] = st2;
      *(float4*)&xbuf[wa[3] + bo_next] = st3;
      *(float4*)&xbuf[wa[4] + bo_next] = st4;
    }
    if (ch < NCH - 2) {
      st0 = *gp[0]; gp[0] += 40; st1 = *gp[1]; gp[1] += 40;
      st2 = *gp[2]; gp[2] += 40; st3 = *gp[3]; gp[3] += 40;
      st4 = *gp[4]; gp[4] += 40;
    }
    const int xb = bo_cur + grp * RSTR;
    rdg(xb +   0, A0v, A1v, A2v, A3v, A4v);
    rdg(xb +  20, B0v, B1v, B2v, B3v, B4v);
    SUBA(); rdg(xb +  40, A0v, A1v, A2v, A3v, A4v);
    SUBB(); rdg(xb +  60, B0v, B1v, B2v, B3v, B4v);
    SUBA(); rdg(xb +  80, A0v, A1v, A2v, A3v, A4v);
    SUBB(); rdg(xb + 100, B0v, B1v, B2v, B3v, B4v);
    SUBA(); rdg(xb + 120, A0v, A1v, A2v, A3v, A4v);
    SUBB(); rdg(xb + 140, B0v, B1v, B2v, B3v, B4v);
    SUBA();
    // cross-chunk: next chunk's first group (dead-garbage for last chunk;
    // the resulting zx values for steps 512/513 are never consumed)
    rdg(bo_next + grp * RSTR, A0v, A1v, A2v, A3v, A4v);
    SUBB();
  }

  // ---- MLP head (single wave; no barriers needed) ----
  float in5_0 = hv0 + xl0, in5_1 = hv1 + xl1, in5_2 = hv2 + xl2,
        in5_3 = hv3 + xl3, in5_4 = hv4 + xl4;

#pragma unroll
  for (int p = 0; p < 4; ++p) {
    int m = p * 8 + j;
    float acc = b1[m];
    acc = fmaf(W1[m * 5 + 0], in5_0, acc);
    acc = fmaf(W1[m * 5 + 1], in5_1, acc);
    acc = fmaf(W1[m * 5 + 2], in5_2, acc);
    acc = fmaf(W1[m * 5 + 3], in5_3, acc);
    acc = fmaf(W1[m * 5 + 4], in5_4, acc);
    s1[grp][m] = fmaxf(acc, 0.0f);
  }
  float y1[32];
#pragma unroll
  for (int k = 0; k < 32; ++k) y1[k] = s1[grp][k];

  auto dot32 = [&](const float* W, int m, const float* y, float b) {
    float acc = b;
    const float4* w4 = (const float4*)(W + m * 32);
#pragma unroll
    for (int k4 = 0; k4 < 8; ++k4) {
      float4 w = w4[k4];
      acc = fmaf(w.x, y[k4 * 4 + 0], acc);
      acc = fmaf(w.y, y[k4 * 4 + 1], acc);
      acc = fmaf(w.z, y[k4 * 4 + 2], acc);
      acc = fmaf(w.w, y[k4 * 4 + 3], acc);
    }
    return acc;
  };

#pragma unroll
  for (int p = 0; p < 4; ++p) {
    int m = p * 8 + j;
    s2[grp][m] = fmaxf(dot32(W2, m, y1, b2[m]), 0.0f);
  }
  float y2[32];
#pragma unroll
  for (int k = 0; k < 32; ++k) y2[k] = s2[grp][k];

  if (act) out[row * HD + j] = dot32(W3, j, y2, b3[j]);
}

extern "C" void kernel_launch(void* const* d_in, const int* in_sizes, int n_in,
                              void* d_out, int out_size, void* d_ws, size_t ws_size,
                              hipStream_t stream) {
  const float* x   = (const float*)d_in[0];
  const float* Wih = (const float*)d_in[1];
  const float* Whh = (const float*)d_in[2];
  const float* bih = (const float*)d_in[3];
  const float* bhh = (const float*)d_in[4];
  const float* W1  = (const float*)d_in[5];
  const float* b1  = (const float*)d_in[6];
  const float* W2  = (const float*)d_in[7];
  const float* b2  = (const float*)d_in[8];
  const float* W3  = (const float*)d_in[9];
  const float* b3  = (const float*)d_in[10];

  int B = in_sizes[0] / (TT * HD);
  int grid = (B + RPB - 1) / RPB;
  hipLaunchKernelGGL(lstm_mlp_kernel, dim3(grid), dim3(64), 0, stream,
                     x, Wih, Whh, bih, bhh, W1, b1, W2, b2, W3, b3,
                     (float*)d_out, B);
}